// Round 1
// baseline (669.501 us; speedup 1.0000x reference)
//
#include <hip/hip_runtime.h>
#include <hip/hip_bf16.h>

// Problem constants:
#define BATCH 8
#define NQ    75
#define WAY   5
#define PN    121
#define DIM   640
#define SSZ   605        // shot * patch_num
#define TOPK  3

#define KCH 10           // DIM / 64
#define NCH 5            // 640 / 128

// Workspace: bf16, MFMA-tile-packed, XOR-swizzled (chunk_phys = chunk_log ^ (row&7)).
//   Q: [bq=600][kc=10] tiles of [row=128][chunk=8]x16B  (6000 tiles)
//   S: [bw=40][nc=5][kc=10] tiles                        (2000 tiles)
#define NQTILES 6000
#define NSTILES 2000
#define WSQ_BYTES ((size_t)NQTILES * 16384)
#define WS_NEED   ((size_t)(NQTILES + NSTILES) * 16384)   // 131,072,000 B

typedef __attribute__((ext_vector_type(8))) short   short8;
typedef __attribute__((ext_vector_type(8))) __bf16  bf16x8;
typedef __attribute__((ext_vector_type(4))) float   f32x4;

__device__ inline unsigned short f2bf(float f) {
  unsigned u = __builtin_bit_cast(unsigned, f);
  return (unsigned short)((u + 0x7fffu + ((u >> 16) & 1u)) >> 16);
}
__device__ inline unsigned pk2(float lo, float hi) {
  return (unsigned)f2bf(lo) | ((unsigned)f2bf(hi) << 16);
}

// branchless insert into sorted-descending triple: 1 max + 2 med3
__device__ inline void ins3(float &a, float &b, float &c, float v) {
  float na  = fmaxf(a, v);
  float nb  = __builtin_amdgcn_fmed3f(v, a, b);
  float nc2 = __builtin_amdgcn_fmed3f(v, b, c);
  a = na; b = nb; c = nc2;
}

// async 16B global->LDS (DMA; LDS dest = wave-uniform base + lane*16)
__device__ inline void async_copy16(const void* g, void* l) {
  __builtin_amdgcn_global_load_lds(
      (const __attribute__((address_space(1))) unsigned int*)g,
      (__attribute__((address_space(3))) unsigned int*)l, 16, 0, 0);
}

// ---------------- pack kernel: fp32 -> swizzled bf16 tiles in ws -------------
// UNCHANGED this round (attribution: isolating the lpc_main pipeline change;
// if lpc_main drops below ~270us, cvt_pack surfaces in rocprof top-5 and we
// get its counters next round).
__global__ __launch_bounds__(256) void cvt_pack(const float* __restrict__ qf,
                                                const float* __restrict__ sf,
                                                uint4* __restrict__ wq,
                                                uint4* __restrict__ wsp) {
  const int blk = blockIdx.x;
  const float* src;
  uint4* dst;
  int nrows;
  if (blk < NQTILES) {
    int kc = blk % KCH;
    int bq = blk / KCH;
    src = qf + (size_t)bq * PN * DIM + kc * 64;
    dst = wq + (size_t)blk * 1024;
    nrows = PN;
  } else {
    int t  = blk - NQTILES;          // ((bw*5 + nc)*10 + kc)
    int kc = t % KCH;
    int u  = t / KCH;
    int nc = u % NCH;
    int bw = u / NCH;
    src = sf + ((size_t)bw * SSZ + nc * 128) * DIM + kc * 64;
    dst = wsp + (size_t)t * 1024;
    nrows = SSZ - nc * 128; if (nrows > 128) nrows = 128;
  }
  #pragma unroll
  for (int i = 0; i < 4; ++i) {
    int ch  = i * 256 + threadIdx.x;   // 0..1023
    int p   = ch & 7;
    int row = ch >> 3;
    int c   = p ^ (row & 7);           // logical chunk for this physical slot
    uint4 o = make_uint4(0u, 0u, 0u, 0u);
    if (row < nrows) {
      const float* g = src + (size_t)row * DIM + c * 8;
      float4 v0 = reinterpret_cast<const float4*>(g)[0];
      float4 v1 = reinterpret_cast<const float4*>(g)[1];
      o.x = pk2(v0.x, v0.y); o.y = pk2(v0.z, v0.w);
      o.z = pk2(v1.x, v1.y); o.w = pk2(v1.z, v1.w);
    }
    dst[ch] = o;
  }
}

// ---------------- main kernel ----------------
// One block per (b,q,w), XCD-swizzled (XCD k owns batch k).
// NEW this round (T3+T4+T5): double-buffered LDS (2x32KB), flattened 50-step
// (nc,kc) loop, depth-2 prefetch with COUNTED s_waitcnt vmcnt(8) + raw
// s_barrier (no vmcnt(0) drain per step — the old __syncthreads() drain was
// the ~900TF structural ceiling), setprio(1) around the MFMA cluster.
// Occupancy 3->2 blocks/CU (64KB LDS); __launch_bounds__(256,2) gives the
// allocator 256 VGPRs (live set ~180, no spills expected).
__global__ __launch_bounds__(256, 2) void lpc_main(
    const char* __restrict__ wq,    // packed Q tiles
    const char* __restrict__ wsp,   // packed S tiles
    float* __restrict__ out)        // [B, NQ, WAY]
{
  __shared__ char Qs[2][16384];
  __shared__ char Ss[2][16384];
  __shared__ float red[4];

  // XCD swizzle: consecutive blockIdx round-robin over 8 XCDs; remap so XCD k
  // processes contiguous bid range [k*375, (k+1)*375) == batch element k.
  const int sbid = blockIdx.x;
  const int bid  = (sbid & 7) * (NQ * WAY) + (sbid >> 3);

  const int w   = bid % WAY;
  const int bq  = bid / WAY;            // b*NQ + q
  const int b   = bid / (WAY * NQ);

  const char* Qtiles = wq  + (size_t)bq * KCH * 16384;
  const char* Stiles = wsp + (size_t)(b * WAY + w) * NCH * KCH * 16384;

  const int tid  = threadIdx.x;
  const int lane = tid & 63;
  const int wv   = tid >> 6;
  const int l15  = lane & 15;
  const int quad = lane >> 4;
  const int mrow0 = (wv >> 1) * 64;     // quadrant row base
  const int ncol0 = (wv & 1) * 64;      // quadrant col base

  // swizzled chunk byte offsets (XOR distributes over the <<4)
  const int sw16 = (l15 & 7) * 16;
  const int cp0  = (quad * 16) ^ sw16;        // kk = 0
  const int cp1  = ((4 + quad) * 16) ^ sw16;  // kk = 1

  const int qoff = (mrow0 + l15) * 128;
  const int soff = (ncol0 + l15) * 128;

  // per-lane running top-3 for 16 owned rows: row = mrow0 + mt*16 + quad*4 + r
  float t3a[4][4], t3b[4][4], t3c[4][4];
  #pragma unroll
  for (int mt = 0; mt < 4; ++mt)
    #pragma unroll
    for (int r = 0; r < 4; ++r) {
      t3a[mt][r] = -3.0e38f; t3b[mt][r] = -3.0e38f; t3c[mt][r] = -3.0e38f;
    }

  // ---- prologue: stage step 0 -> buf0, step 1 -> buf1 (16 DMA ops/wave) ----
  {
    #pragma unroll
    for (int i = 0; i < 4; ++i) {
      const int ch = wv * 4 + i;
      const int go = ch * 1024 + lane * 16;
      async_copy16(Qtiles + go, &Qs[0][ch * 1024]);
      async_copy16(Stiles + go, &Ss[0][ch * 1024]);
    }
    #pragma unroll
    for (int i = 0; i < 4; ++i) {
      const int ch = wv * 4 + i;
      const int go = ch * 1024 + lane * 16;
      async_copy16(Qtiles + 16384 + go, &Qs[1][ch * 1024]);
      async_copy16(Stiles + 16384 + go, &Ss[1][ch * 1024]);
    }
  }

  f32x4 acc[4][4];
  int nc = 0;          // current 128-col S chunk (fold boundary tracker)
  int kc = 0;          // position within K for current nc (0..9)
  int kc2 = 2;         // kc of step t+2 (Q tile index for prefetch)

  // 50 flattened K-steps; S tile index == t (S slab is linear in (nc,kc)).
  #pragma unroll 1
  for (int t = 0; t < NCH * KCH; ++t) {
    const int cur = t & 1;

    if (kc == 0) {   // register-only; overlaps in-flight DMA
      #pragma unroll
      for (int mt = 0; mt < 4; ++mt)
        #pragma unroll
        for (int nt = 0; nt < 4; ++nt)
          acc[mt][nt] = (f32x4){0.f, 0.f, 0.f, 0.f};
    }

    // Counted wait: outstanding = stage(t) + stage(t+1) = 16 ops; vmcnt(8)
    // retires stage(t) (in-order retirement), leaves stage(t+1) IN FLIGHT
    // across the barrier. Only the final step drains.
    if (t < 49) asm volatile("s_waitcnt vmcnt(8)" ::: "memory");
    else        asm volatile("s_waitcnt vmcnt(0)" ::: "memory");
    asm volatile("s_barrier" ::: "memory");   // raw: no compiler vmcnt(0) drain

    const char* qb = &Qs[cur][0] + qoff;
    const char* sb = &Ss[cur][0] + soff;

    __builtin_amdgcn_s_setprio(1);
    #pragma unroll
    for (int kk = 0; kk < 2; ++kk) {
      const int cp = kk ? cp1 : cp0;
      short8 a[4], bf[4];
      #pragma unroll
      for (int mt = 0; mt < 4; ++mt)
        a[mt] = *reinterpret_cast<const short8*>(qb + mt * 2048 + cp);
      #pragma unroll
      for (int nt = 0; nt < 4; ++nt)
        bf[nt] = *reinterpret_cast<const short8*>(sb + nt * 2048 + cp);
      #pragma unroll
      for (int mt = 0; mt < 4; ++mt)
        #pragma unroll
        for (int nt = 0; nt < 4; ++nt)
          acc[mt][nt] = __builtin_amdgcn_mfma_f32_16x16x32_bf16(
              __builtin_bit_cast(bf16x8, a[mt]),
              __builtin_bit_cast(bf16x8, bf[nt]), acc[mt][nt], 0, 0, 0);
    }
    __builtin_amdgcn_s_setprio(0);

    // All waves done reading buf[cur] before anyone overwrites it.
    asm volatile("s_barrier" ::: "memory");

    if (t < 48) {   // issue stage(t+2) into the buffer just consumed
      const char* qsl = Qtiles + kc2 * 16384;
      const char* ssl = Stiles + (size_t)(t + 2) * 16384;
      #pragma unroll
      for (int i = 0; i < 4; ++i) {
        const int ch = wv * 4 + i;
        const int go = ch * 1024 + lane * 16;
        async_copy16(qsl + go, &Qs[cur][ch * 1024]);
        async_copy16(ssl + go, &Ss[cur][ch * 1024]);
      }
    }
    kc2 = (kc2 == 9) ? 0 : kc2 + 1;

    if (kc == 9) {
      // fold this 128-col chunk into register top-3 (mask pad cols >= 605);
      // register-only, overlaps the just-issued DMA.
      #pragma unroll
      for (int nt = 0; nt < 4; ++nt) {
        const int col = nc * 128 + ncol0 + nt * 16 + l15;
        const bool valid = col < SSZ;
        #pragma unroll
        for (int mt = 0; mt < 4; ++mt)
          #pragma unroll
          for (int r = 0; r < 4; ++r) {
            float v = valid ? acc[mt][nt][r] : -3.0e38f;
            ins3(t3a[mt][r], t3b[mt][r], t3c[mt][r], v);
          }
      }
      ++nc; kc = 0;
    } else {
      ++kc;
    }
  }

  // butterfly-merge top-3 across the 16 l15 lanes (same rows, different cols)
  #pragma unroll
  for (int m = 1; m < 16; m <<= 1) {
    #pragma unroll
    for (int mt = 0; mt < 4; ++mt)
      #pragma unroll
      for (int r = 0; r < 4; ++r) {
        float o0 = __shfl_xor(t3a[mt][r], m);
        float o1 = __shfl_xor(t3b[mt][r], m);
        float o2 = __shfl_xor(t3c[mt][r], m);
        ins3(t3a[mt][r], t3b[mt][r], t3c[mt][r], o0);
        ins3(t3a[mt][r], t3b[mt][r], t3c[mt][r], o1);
        ins3(t3a[mt][r], t3b[mt][r], t3c[mt][r], o2);
      }
  }

  // cross-half merge via LDS scratch (reuse Qs): waves 1,3 publish; 0,2 merge
  float* tb = reinterpret_cast<float*>(&Qs[0][0]);   // [128][3]
  __syncthreads();
  if ((wv & 1) == 1 && l15 == 0) {
    #pragma unroll
    for (int mt = 0; mt < 4; ++mt)
      #pragma unroll
      for (int r = 0; r < 4; ++r) {
        int row = mrow0 + mt * 16 + quad * 4 + r;
        tb[row * 3 + 0] = t3a[mt][r];
        tb[row * 3 + 1] = t3b[mt][r];
        tb[row * 3 + 2] = t3c[mt][r];
      }
  }
  __syncthreads();
  if ((wv & 1) == 0 && l15 == 0) {
    #pragma unroll
    for (int mt = 0; mt < 4; ++mt)
      #pragma unroll
      for (int r = 0; r < 4; ++r) {
        int row = mrow0 + mt * 16 + quad * 4 + r;
        ins3(t3a[mt][r], t3b[mt][r], t3c[mt][r], tb[row * 3 + 0]);
        ins3(t3a[mt][r], t3b[mt][r], t3c[mt][r], tb[row * 3 + 1]);
        ins3(t3a[mt][r], t3b[mt][r], t3c[mt][r], tb[row * 3 + 2]);
      }
  }
  __syncthreads();
  if ((wv & 1) == 0 && l15 == 0) {
    #pragma unroll
    for (int mt = 0; mt < 4; ++mt)
      #pragma unroll
      for (int r = 0; r < 4; ++r) {
        int row = mrow0 + mt * 16 + quad * 4 + r;
        tb[row * 3 + 0] = t3a[mt][r];
        tb[row * 3 + 1] = t3b[mt][r];
        tb[row * 3 + 2] = t3c[mt][r];
      }
  }
  __syncthreads();

  // mean over valid rows (<121) and k
  float s = 0.f;
  for (int i = tid; i < PN * TOPK; i += 256) s += tb[i];
  #pragma unroll
  for (int off = 32; off > 0; off >>= 1) s += __shfl_down(s, off);
  if (lane == 0) red[wv] = s;
  __syncthreads();
  if (tid == 0)
    out[bid] = (red[0] + red[1] + red[2] + red[3]) * (1.0f / (PN * TOPK));
}

// ---------------- fallback (direct from fp32, only if ws too small) ---------
__global__ __launch_bounds__(256) void lpc_fallback(
    const float* __restrict__ qf, const float* __restrict__ sf,
    float* __restrict__ out)
{
  __shared__ short Qst[128][72];
  __shared__ short Sst[64][72];
  __shared__ float Cs[128][67];
  __shared__ float top3[128][TOPK];
  __shared__ float red[4];

  const int bid = blockIdx.x;
  const int w   = bid % WAY;
  const int qi  = (bid / WAY) % NQ;
  const int b   = bid / (WAY * NQ);
  const float* Qb = qf + ((size_t)(b * NQ + qi)) * PN * DIM;
  const float* Sb = sf + ((size_t)(b * WAY + w)) * SSZ * DIM;
  const int tid  = threadIdx.x;
  const int lane = tid & 63;
  const int wv   = tid >> 6;
  const int l15  = lane & 15;
  const int quad = lane >> 4;

  if (tid < 128) { top3[tid][0] = -3.0e38f; top3[tid][1] = -3.0e38f; top3[tid][2] = -3.0e38f; }
  f32x4 acc[2][4];
  for (int nc = 0; nc < 10; ++nc) {
    const int sbase = nc * 64;
    int vn = SSZ - sbase; if (vn > 64) vn = 64;
    #pragma unroll
    for (int mt = 0; mt < 2; ++mt)
      #pragma unroll
      for (int nt = 0; nt < 4; ++nt) acc[mt][nt] = (f32x4){0.f,0.f,0.f,0.f};
    for (int kc = 0; kc < KCH; ++kc) {
      const int kbase = kc * 64;
      __syncthreads();
      #pragma unroll
      for (int i = 0; i < 8; ++i) {
        int lin = i * 256 + tid; int row = lin >> 4; int c4 = lin & 15;
        float4 v = make_float4(0.f,0.f,0.f,0.f);
        if (row < PN) v = *reinterpret_cast<const float4*>(Qb + (size_t)row * DIM + kbase + c4 * 4);
        ushort4 h; h.x=f2bf(v.x); h.y=f2bf(v.y); h.z=f2bf(v.z); h.w=f2bf(v.w);
        *reinterpret_cast<ushort4*>(&Qst[row][c4*4]) = h;
      }
      #pragma unroll
      for (int i = 0; i < 4; ++i) {
        int lin = i * 256 + tid; int row = lin >> 4; int c4 = lin & 15;
        int srow = sbase + row;
        float4 v = make_float4(0.f,0.f,0.f,0.f);
        if (srow < SSZ) v = *reinterpret_cast<const float4*>(Sb + (size_t)srow * DIM + kbase + c4 * 4);
        ushort4 h; h.x=f2bf(v.x); h.y=f2bf(v.y); h.z=f2bf(v.z); h.w=f2bf(v.w);
        *reinterpret_cast<ushort4*>(&Sst[row][c4*4]) = h;
      }
      __syncthreads();
      #pragma unroll
      for (int kk = 0; kk < 2; ++kk) {
        bf16x8 a0 = __builtin_bit_cast(bf16x8, *reinterpret_cast<const short8*>(&Qst[wv*32+ 0+l15][kk*32+quad*8]));
        bf16x8 a1 = __builtin_bit_cast(bf16x8, *reinterpret_cast<const short8*>(&Qst[wv*32+16+l15][kk*32+quad*8]));
        #pragma unroll
        for (int nt = 0; nt < 4; ++nt) {
          bf16x8 bb = __builtin_bit_cast(bf16x8, *reinterpret_cast<const short8*>(&Sst[nt*16+l15][kk*32+quad*8]));
          acc[0][nt] = __builtin_amdgcn_mfma_f32_16x16x32_bf16(a0, bb, acc[0][nt], 0,0,0);
          acc[1][nt] = __builtin_amdgcn_mfma_f32_16x16x32_bf16(a1, bb, acc[1][nt], 0,0,0);
        }
      }
    }
    #pragma unroll
    for (int mt = 0; mt < 2; ++mt)
      #pragma unroll
      for (int nt = 0; nt < 4; ++nt)
        #pragma unroll
        for (int r = 0; r < 4; ++r)
          Cs[wv*32+mt*16+quad*4+r][nt*16+l15] = acc[mt][nt][r];
    __syncthreads();
    {
      int row = tid >> 1; int half = tid & 1;
      float a = -3.0e38f, b2 = -3.0e38f, c = -3.0e38f;
      int c0 = half * 32; int cend = c0 + 32; if (cend > vn) cend = vn;
      for (int cc = c0; cc < cend; ++cc) ins3(a, b2, c, Cs[row][cc]);
      float o0 = __shfl_xor(a,1), o1 = __shfl_xor(b2,1), o2 = __shfl_xor(c,1);
      ins3(a,b2,c,o0); ins3(a,b2,c,o1); ins3(a,b2,c,o2);
      if (half == 0) {
        float r0=top3[row][0], r1=top3[row][1], r2=top3[row][2];
        ins3(r0,r1,r2,a); ins3(r0,r1,r2,b2); ins3(r0,r1,r2,c);
        top3[row][0]=r0; top3[row][1]=r1; top3[row][2]=r2;
      }
    }
    __syncthreads();
  }
  float s = 0.f;
  for (int i = tid; i < PN * TOPK; i += 256) s += top3[i/TOPK][i%TOPK];
  #pragma unroll
  for (int off = 32; off > 0; off >>= 1) s += __shfl_down(s, off);
  if (lane == 0) red[wv] = s;
  __syncthreads();
  if (tid == 0) out[bid] = (red[0]+red[1]+red[2]+red[3]) * (1.0f/(PN*TOPK));
}

// ---------------- launch ----------------
extern "C" void kernel_launch(void* const* d_in, const int* in_sizes, int n_in,
                              void* d_out, int out_size, void* d_ws, size_t ws_size,
                              hipStream_t stream) {
  const float* qf = (const float*)d_in[0];
  const float* sf = (const float*)d_in[1];
  float* out = (float*)d_out;
  (void)in_sizes; (void)n_in; (void)out_size;

  if (ws_size >= WS_NEED && d_ws != nullptr) {
    uint4* wq  = (uint4*)d_ws;
    uint4* wsp = wq + (size_t)NQTILES * 1024;
    cvt_pack<<<NQTILES + NSTILES, 256, 0, stream>>>(qf, sf, wq, wsp);
    lpc_main<<<BATCH * NQ * WAY, 256, 0, stream>>>((const char*)wq, (const char*)wsp, out);
  } else {
    lpc_fallback<<<BATCH * NQ * WAY, 256, 0, stream>>>(qf, sf, out);
  }
}

// Round 3
// 627.325 us; speedup vs baseline: 1.0672x; 1.0672x over previous
//
#include <hip/hip_runtime.h>
#include <hip/hip_bf16.h>

// Problem constants:
#define BATCH 8
#define NQ    75
#define WAY   5
#define PN    121
#define DIM   640
#define SSZ   605        // shot * patch_num
#define TOPK  3

#define KCH 10           // DIM / 64
#define NCH 5            // 640 / 128

// Workspace: bf16, MFMA-tile-packed, XOR-swizzled (chunk_phys = chunk_log ^ (row&7)).
//   Q: [bq=600][kc=10] tiles of [row=128][chunk=8]x16B  (6000 tiles)
//   S: [bw=40][nc=5][kc=10] tiles                        (2000 tiles)
#define NQTILES 6000
#define NSTILES 2000
#define WSQ_BYTES ((size_t)NQTILES * 16384)
#define WS_NEED   ((size_t)(NQTILES + NSTILES) * 16384)   // 131,072,000 B

typedef __attribute__((ext_vector_type(8))) short   short8;
typedef __attribute__((ext_vector_type(8))) __bf16  bf16x8;
typedef __attribute__((ext_vector_type(4))) float   f32x4;

__device__ inline unsigned short f2bf(float f) {
  unsigned u = __builtin_bit_cast(unsigned, f);
  return (unsigned short)((u + 0x7fffu + ((u >> 16) & 1u)) >> 16);
}
__device__ inline unsigned pk2(float lo, float hi) {
  return (unsigned)f2bf(lo) | ((unsigned)f2bf(hi) << 16);
}

// branchless insert into sorted-descending triple: 1 max + 2 med3
__device__ inline void ins3(float &a, float &b, float &c, float v) {
  float na  = fmaxf(a, v);
  float nb  = __builtin_amdgcn_fmed3f(v, a, b);
  float nc2 = __builtin_amdgcn_fmed3f(v, b, c);
  a = na; b = nb; c = nc2;
}

// async 16B global->LDS (DMA; LDS dest = wave-uniform base + lane*16)
__device__ inline void async_copy16(const void* g, void* l) {
  __builtin_amdgcn_global_load_lds(
      (const __attribute__((address_space(1))) unsigned int*)g,
      (__attribute__((address_space(3))) unsigned int*)l, 16, 0, 0);
}

// ---------------- pack kernel: fp32 -> swizzled bf16 tiles in ws -------------
// Read-side restructure (round-1 change, unmeasured due to container failure):
// old version = 1 block per (slab,kc) tile, reading 256B slices at 2560B
// stride scattered across XCDs -> ~1.5 TB/s (24% of achievable; ~260us vs
// 60us roofline). New version = 1 block per 64-row slab half, reading a
// CONTIGUOUS ~160KB stream and emitting all 10 kc tiles for its rows.
// Output bytes identical (same f2bf/pk2/XOR-swizzle), so lpc_main untouched.
// Writes: 8x fully-covered 128B lines per wave store (same line count).
//   blk in [0,1200):    Q slab half: slab=blk>>1 (bq), rows [64*(blk&1), +64)
//   blk in [1200,1600): S slab half: u=blk-1200, (bw*5+nc)=u>>1, half=u&1
__global__ __launch_bounds__(256) void cvt_pack(const float* __restrict__ qf,
                                                const float* __restrict__ sf,
                                                uint4* __restrict__ wq,
                                                uint4* __restrict__ wsp) {
  const int blk = blockIdx.x;
  const float* src;      // slab base (row 0 of the 128-row tile frame)
  uint4* dstbase;        // first kc tile of this slab
  int nrows;             // valid rows in the 128-row tile frame
  int rowbase;           // 0 or 64
  if (blk < 1200) {
    const int slab = blk >> 1;
    rowbase = (blk & 1) << 6;
    src = qf + (size_t)slab * PN * DIM;
    dstbase = wq + (size_t)slab * KCH * 1024;
    nrows = PN;
  } else {
    const int u  = blk - 1200;
    const int uv = u >> 1;              // bw*5 + nc
    rowbase = (u & 1) << 6;
    const int nc = uv % NCH;
    const int bw = uv / NCH;
    src = sf + ((size_t)bw * SSZ + nc * 128) * DIM;
    dstbase = wsp + (size_t)uv * KCH * 1024;
    nrows = SSZ - nc * 128; if (nrows > 128) nrows = 128;
  }
  // 64 rows x 80 segments (8 floats in, 16B out each) = 5120 segs, 20 iters.
  // Consecutive threads -> consecutive 32B input segments (streaming reads).
  #pragma unroll 4
  for (int i = 0; i < 20; ++i) {
    const int L    = i * 256 + threadIdx.x;   // 0..5119
    const int rowl = L / 80;                  // magic-mul div
    const int s    = L - rowl * 80;           // 0..79: global 8-float segment
    const int row  = rowbase + rowl;          // tile-local row 0..127
    const int kc   = s >> 3;
    const int c    = s & 7;                   // logical chunk within kc window
    const int p    = c ^ (row & 7);           // physical chunk slot (swizzle)
    uint4 o = make_uint4(0u, 0u, 0u, 0u);
    if (row < nrows) {
      const float* g = src + (size_t)row * DIM + s * 8;
      float4 v0 = reinterpret_cast<const float4*>(g)[0];
      float4 v1 = reinterpret_cast<const float4*>(g)[1];
      o.x = pk2(v0.x, v0.y); o.y = pk2(v0.z, v0.w);
      o.z = pk2(v1.x, v1.y); o.w = pk2(v1.z, v1.w);
    }
    dstbase[(size_t)kc * 1024 + row * 8 + p] = o;
  }
}

// ---------------- main kernel ----------------
// Round-0 structure (measured 348us, MfmaUtil 40.6, 904 TF on padded work).
// Round-1 post-mortem: 64KB-LDS double-buffer + counted vmcnt(8) pipeline cost
// a block/CU (3->2) and LOST 18% — inter-block implicit overlap at 3 blocks/CU
// beats the intra-block pipeline at this tile size. Keep the 2-barrier
// single-buffer structure.
// One block per (b,q,w), XCD-swizzled so XCD k owns b=k (per-XCD working set:
// 5 S slabs = 4 MB = one L2, plus one 160 KB Q slab shared by 5 w-blocks).
// 4 waves = 64x64 quadrants; DMA staging; XOR-swizzled LDS reads (0 conflicts);
// per-row top-3 in registers.
// __launch_bounds__(256,3): reg cap 170 = 64 AGPR acc + ~106 VGPR — fits the
// live set (t3=48, frags=32, addr) with NO spills; (256,4) capped at 128 and
// spilled 246 MB.
__global__ __launch_bounds__(256, 3) void lpc_main(
    const char* __restrict__ wq,    // packed Q tiles
    const char* __restrict__ wsp,   // packed S tiles
    float* __restrict__ out)        // [B, NQ, WAY]
{
  __shared__ char Qs[16384];
  __shared__ char Ss[16384];
  __shared__ float red[4];

  // XCD swizzle: consecutive blockIdx round-robin over 8 XCDs; remap so XCD k
  // processes contiguous bid range [k*375, (k+1)*375) == batch element k.
  const int sbid = blockIdx.x;
  const int bid  = (sbid & 7) * (NQ * WAY) + (sbid >> 3);

  const int w   = bid % WAY;
  const int bq  = bid / WAY;            // b*NQ + q
  const int b   = bid / (WAY * NQ);

  const char* Qtiles = wq  + (size_t)bq * KCH * 16384;
  const char* Stiles = wsp + (size_t)(b * WAY + w) * NCH * KCH * 16384;

  const int tid  = threadIdx.x;
  const int lane = tid & 63;
  const int wv   = tid >> 6;
  const int l15  = lane & 15;
  const int quad = lane >> 4;
  const int mrow0 = (wv >> 1) * 64;     // quadrant row base
  const int ncol0 = (wv & 1) * 64;      // quadrant col base

  // swizzled chunk byte offsets (XOR distributes over the <<4)
  const int sw16 = (l15 & 7) * 16;
  const int cp0  = (quad * 16) ^ sw16;        // kk = 0
  const int cp1  = ((4 + quad) * 16) ^ sw16;  // kk = 1

  const char* qb = Qs + (mrow0 + l15) * 128;
  const char* sb = Ss + (ncol0 + l15) * 128;

  // per-lane running top-3 for 16 owned rows: row = mrow0 + mt*16 + quad*4 + r
  float t3a[4][4], t3b[4][4], t3c[4][4];
  #pragma unroll
  for (int mt = 0; mt < 4; ++mt)
    #pragma unroll
    for (int r = 0; r < 4; ++r) {
      t3a[mt][r] = -3.0e38f; t3b[mt][r] = -3.0e38f; t3c[mt][r] = -3.0e38f;
    }

  for (int nc = 0; nc < NCH; ++nc) {
    f32x4 acc[4][4];
    #pragma unroll
    for (int mt = 0; mt < 4; ++mt)
      #pragma unroll
      for (int nt = 0; nt < 4; ++nt)
        acc[mt][nt] = (f32x4){0.f, 0.f, 0.f, 0.f};

    #pragma unroll 1
    for (int kc = 0; kc < KCH; ++kc) {
      __syncthreads();   // previous iteration's readers done
      {
        const char* qsl = Qtiles + (size_t)kc * 16384;
        const char* ssl = Stiles + ((size_t)nc * KCH + kc) * 16384;
        #pragma unroll
        for (int i = 0; i < 4; ++i) {
          int ch = wv * 4 + i;
          async_copy16(qsl + ch * 1024 + lane * 16, Qs + ch * 1024);
          async_copy16(ssl + ch * 1024 + lane * 16, Ss + ch * 1024);
        }
      }
      __syncthreads();   // drains vmcnt (DMA complete)

      #pragma unroll
      for (int kk = 0; kk < 2; ++kk) {
        const int cp = kk ? cp1 : cp0;
        short8 a[4], bf[4];
        #pragma unroll
        for (int mt = 0; mt < 4; ++mt)
          a[mt] = *reinterpret_cast<const short8*>(qb + mt * 2048 + cp);
        #pragma unroll
        for (int nt = 0; nt < 4; ++nt)
          bf[nt] = *reinterpret_cast<const short8*>(sb + nt * 2048 + cp);
        #pragma unroll
        for (int mt = 0; mt < 4; ++mt)
          #pragma unroll
          for (int nt = 0; nt < 4; ++nt)
            acc[mt][nt] = __builtin_amdgcn_mfma_f32_16x16x32_bf16(
                __builtin_bit_cast(bf16x8, a[mt]),
                __builtin_bit_cast(bf16x8, bf[nt]), acc[mt][nt], 0, 0, 0);
      }
    }

    // fold this 128-col chunk into register top-3 (mask pad cols >= 605)
    #pragma unroll
    for (int nt = 0; nt < 4; ++nt) {
      int col = nc * 128 + ncol0 + nt * 16 + l15;
      bool valid = col < SSZ;
      #pragma unroll
      for (int mt = 0; mt < 4; ++mt)
        #pragma unroll
        for (int r = 0; r < 4; ++r) {
          float v = valid ? acc[mt][nt][r] : -3.0e38f;
          ins3(t3a[mt][r], t3b[mt][r], t3c[mt][r], v);
        }
    }
  }

  // butterfly-merge top-3 across the 16 l15 lanes (same rows, different cols)
  #pragma unroll
  for (int m = 1; m < 16; m <<= 1) {
    #pragma unroll
    for (int mt = 0; mt < 4; ++mt)
      #pragma unroll
      for (int r = 0; r < 4; ++r) {
        float o0 = __shfl_xor(t3a[mt][r], m);
        float o1 = __shfl_xor(t3b[mt][r], m);
        float o2 = __shfl_xor(t3c[mt][r], m);
        ins3(t3a[mt][r], t3b[mt][r], t3c[mt][r], o0);
        ins3(t3a[mt][r], t3b[mt][r], t3c[mt][r], o1);
        ins3(t3a[mt][r], t3b[mt][r], t3c[mt][r], o2);
      }
  }

  // cross-half merge via LDS scratch (reuse Qs): waves 1,3 publish; 0,2 merge
  float* tb = reinterpret_cast<float*>(Qs);   // [128][3]
  __syncthreads();
  if ((wv & 1) == 1 && l15 == 0) {
    #pragma unroll
    for (int mt = 0; mt < 4; ++mt)
      #pragma unroll
      for (int r = 0; r < 4; ++r) {
        int row = mrow0 + mt * 16 + quad * 4 + r;
        tb[row * 3 + 0] = t3a[mt][r];
        tb[row * 3 + 1] = t3b[mt][r];
        tb[row * 3 + 2] = t3c[mt][r];
      }
  }
  __syncthreads();
  if ((wv & 1) == 0 && l15 == 0) {
    #pragma unroll
    for (int mt = 0; mt < 4; ++mt)
      #pragma unroll
      for (int r = 0; r < 4; ++r) {
        int row = mrow0 + mt * 16 + quad * 4 + r;
        ins3(t3a[mt][r], t3b[mt][r], t3c[mt][r], tb[row * 3 + 0]);
        ins3(t3a[mt][r], t3b[mt][r], t3c[mt][r], tb[row * 3 + 1]);
        ins3(t3a[mt][r], t3b[mt][r], t3c[mt][r], tb[row * 3 + 2]);
      }
  }
  __syncthreads();
  if ((wv & 1) == 0 && l15 == 0) {
    #pragma unroll
    for (int mt = 0; mt < 4; ++mt)
      #pragma unroll
      for (int r = 0; r < 4; ++r) {
        int row = mrow0 + mt * 16 + quad * 4 + r;
        tb[row * 3 + 0] = t3a[mt][r];
        tb[row * 3 + 1] = t3b[mt][r];
        tb[row * 3 + 2] = t3c[mt][r];
      }
  }
  __syncthreads();

  // mean over valid rows (<121) and k
  float s = 0.f;
  for (int i = tid; i < PN * TOPK; i += 256) s += tb[i];
  #pragma unroll
  for (int off = 32; off > 0; off >>= 1) s += __shfl_down(s, off);
  if (lane == 0) red[wv] = s;
  __syncthreads();
  if (tid == 0)
    out[bid] = (red[0] + red[1] + red[2] + red[3]) * (1.0f / (PN * TOPK));
}

// ---------------- fallback (direct from fp32, only if ws too small) ---------
__global__ __launch_bounds__(256) void lpc_fallback(
    const float* __restrict__ qf, const float* __restrict__ sf,
    float* __restrict__ out)
{
  __shared__ short Qst[128][72];
  __shared__ short Sst[64][72];
  __shared__ float Cs[128][67];
  __shared__ float top3[128][TOPK];
  __shared__ float red[4];

  const int bid = blockIdx.x;
  const int w   = bid % WAY;
  const int qi  = (bid / WAY) % NQ;
  const int b   = bid / (WAY * NQ);
  const float* Qb = qf + ((size_t)(b * NQ + qi)) * PN * DIM;
  const float* Sb = sf + ((size_t)(b * WAY + w)) * SSZ * DIM;
  const int tid  = threadIdx.x;
  const int lane = tid & 63;
  const int wv   = tid >> 6;
  const int l15  = lane & 15;
  const int quad = lane >> 4;

  if (tid < 128) { top3[tid][0] = -3.0e38f; top3[tid][1] = -3.0e38f; top3[tid][2] = -3.0e38f; }
  f32x4 acc[2][4];
  for (int nc = 0; nc < 10; ++nc) {
    const int sbase = nc * 64;
    int vn = SSZ - sbase; if (vn > 64) vn = 64;
    #pragma unroll
    for (int mt = 0; mt < 2; ++mt)
      #pragma unroll
      for (int nt = 0; nt < 4; ++nt) acc[mt][nt] = (f32x4){0.f,0.f,0.f,0.f};
    for (int kc = 0; kc < KCH; ++kc) {
      const int kbase = kc * 64;
      __syncthreads();
      #pragma unroll
      for (int i = 0; i < 8; ++i) {
        int lin = i * 256 + tid; int row = lin >> 4; int c4 = lin & 15;
        float4 v = make_float4(0.f,0.f,0.f,0.f);
        if (row < PN) v = *reinterpret_cast<const float4*>(Qb + (size_t)row * DIM + kbase + c4 * 4);
        ushort4 h; h.x=f2bf(v.x); h.y=f2bf(v.y); h.z=f2bf(v.z); h.w=f2bf(v.w);
        *reinterpret_cast<ushort4*>(&Qst[row][c4*4]) = h;
      }
      #pragma unroll
      for (int i = 0; i < 4; ++i) {
        int lin = i * 256 + tid; int row = lin >> 4; int c4 = lin & 15;
        int srow = sbase + row;
        float4 v = make_float4(0.f,0.f,0.f,0.f);
        if (srow < SSZ) v = *reinterpret_cast<const float4*>(Sb + (size_t)srow * DIM + kbase + c4 * 4);
        ushort4 h; h.x=f2bf(v.x); h.y=f2bf(v.y); h.z=f2bf(v.z); h.w=f2bf(v.w);
        *reinterpret_cast<ushort4*>(&Sst[row][c4*4]) = h;
      }
      __syncthreads();
      #pragma unroll
      for (int kk = 0; kk < 2; ++kk) {
        bf16x8 a0 = __builtin_bit_cast(bf16x8, *reinterpret_cast<const short8*>(&Qst[wv*32+ 0+l15][kk*32+quad*8]));
        bf16x8 a1 = __builtin_bit_cast(bf16x8, *reinterpret_cast<const short8*>(&Qst[wv*32+16+l15][kk*32+quad*8]));
        #pragma unroll
        for (int nt = 0; nt < 4; ++nt) {
          bf16x8 bb = __builtin_bit_cast(bf16x8, *reinterpret_cast<const short8*>(&Sst[nt*16+l15][kk*32+quad*8]));
          acc[0][nt] = __builtin_amdgcn_mfma_f32_16x16x32_bf16(a0, bb, acc[0][nt], 0,0,0);
          acc[1][nt] = __builtin_amdgcn_mfma_f32_16x16x32_bf16(a1, bb, acc[1][nt], 0,0,0);
        }
      }
    }
    #pragma unroll
    for (int mt = 0; mt < 2; ++mt)
      #pragma unroll
      for (int nt = 0; nt < 4; ++nt)
        #pragma unroll
        for (int r = 0; r < 4; ++r)
          Cs[wv*32+mt*16+quad*4+r][nt*16+l15] = acc[mt][nt][r];
    __syncthreads();
    {
      int row = tid >> 1; int half = tid & 1;
      float a = -3.0e38f, b2 = -3.0e38f, c = -3.0e38f;
      int c0 = half * 32; int cend = c0 + 32; if (cend > vn) cend = vn;
      for (int cc = c0; cc < cend; ++cc) ins3(a, b2, c, Cs[row][cc]);
      float o0 = __shfl_xor(a,1), o1 = __shfl_xor(b2,1), o2 = __shfl_xor(c,1);
      ins3(a,b2,c,o0); ins3(a,b2,c,o1); ins3(a,b2,c,o2);
      if (half == 0) {
        float r0=top3[row][0], r1=top3[row][1], r2=top3[row][2];
        ins3(r0,r1,r2,a); ins3(r0,r1,r2,b2); ins3(r0,r1,r2,c);
        top3[row][0]=r0; top3[row][1]=r1; top3[row][2]=r2;
      }
    }
    __syncthreads();
  }
  float s = 0.f;
  for (int i = tid; i < PN * TOPK; i += 256) s += top3[i/TOPK][i%TOPK];
  #pragma unroll
  for (int off = 32; off > 0; off >>= 1) s += __shfl_down(s, off);
  if (lane == 0) red[wv] = s;
  __syncthreads();
  if (tid == 0) out[bid] = (red[0]+red[1]+red[2]+red[3]) * (1.0f/(PN*TOPK));
}

// ---------------- launch ----------------
extern "C" void kernel_launch(void* const* d_in, const int* in_sizes, int n_in,
                              void* d_out, int out_size, void* d_ws, size_t ws_size,
                              hipStream_t stream) {
  const float* qf = (const float*)d_in[0];
  const float* sf = (const float*)d_in[1];
  float* out = (float*)d_out;
  (void)in_sizes; (void)n_in; (void)out_size;

  if (ws_size >= WS_NEED && d_ws != nullptr) {
    uint4* wq  = (uint4*)d_ws;
    uint4* wsp = wq + (size_t)NQTILES * 1024;
    cvt_pack<<<1600, 256, 0, stream>>>(qf, sf, wq, wsp);
    lpc_main<<<BATCH * NQ * WAY, 256, 0, stream>>>((const char*)wq, (const char*)wsp, out);
  } else {
    lpc_fallback<<<BATCH * NQ * WAY, 256, 0, stream>>>(qf, sf, out);
  }
}